// Round 6
// baseline (539.532 us; speedup 1.0000x reference)
//
#include <hip/hip_runtime.h>
#include <math.h>

// Qwen3 MoE gate: logits = hidden @ W_gate^T ; softmax ; top-8 ; renorm.
// Outputs (flat f32): sel_w [T*8], sel_idx-as-float [T*8], logits [T*64].
//
// R6 = R5 structure with the spill fixed: __launch_bounds__(512,1).
// R5's (512,2) empirically capped VGPR at 128 (hipcc: 2nd arg ~ min
// blocks/CU -> 4 waves/EU -> 128) and the 8x8 tile (~190 VGPR) spilled:
// WRITE_SIZE 1.07 GB, FETCH 650 MB, VALUBusy 8%. With cap 256 the tile
// fits in registers. Everything else identical (it passed): 8x8 thread
// tile, 8-way k-split, [64][20]-padded per-wave LDS tiles (compute reads
// hit all 32 banks exactly once, 8-way broadcast free), T14 staging,
// LDS tree reduce + fused logits/top-9/flag epilogue; fp64 fixup pass.

#define HDIM 2048
#define NEXP 64
#define TOPK 8
#define NSCAN 9
#define TAU  2.5e-4f

#define KSPLIT 8
#define KWIN  (HDIM / KSPLIT)   // 256 k per wave
#define BK    16                // k per staged chunk
#define NCH   (KWIN / BK)       // 16 chunks
#define TROW  20                // tile row stride (floats): 16 + 4 pad
#define TILEF (64 * TROW)       // 1280 floats per tile
#define WVF   (2 * TILEF)       // 2560 floats per wave (H + W)
#define RROW  68                // reduce row stride (floats)
#define RSL   (64 * RROW)       // 4352 floats per reduce slice

__global__ __launch_bounds__(512, 1) void gate_fused(
    const float* __restrict__ hidden,   // [T, 2048]
    const float* __restrict__ wgate,    // [64, 2048]
    float* __restrict__ logits,         // [T, 64]
    float* __restrict__ selw,           // [T, 8]
    float* __restrict__ selidx,         // [T, 8]
    int* __restrict__ cnt,
    int* __restrict__ list)
{
    __shared__ float lds[KSPLIT * WVF];   // 20480 floats = 80 KiB

    const int tid  = threadIdx.x;
    const int lane = tid & 63;
    const int wv   = __builtin_amdgcn_readfirstlane(tid >> 6);
    const int tg   = lane & 7;     // token group: tokens tg + 8i
    const int eg   = lane >> 3;    // expert group: experts eg + 8j
    const size_t tokBase = (size_t)blockIdx.x * 64;
    const int kw   = wv * KWIN;

    float* Ht = &lds[wv * WVF];
    float* Wt = Ht + TILEF;

    float acc[8][8];
#pragma unroll
    for (int i = 0; i < 8; ++i)
#pragma unroll
        for (int j = 0; j < 8; ++j) acc[i][j] = 0.f;

    // staging map: float4 g = p*64+lane -> row p*16+(lane>>2), c4 = lane&3.
    const int srow = lane >> 2;
    const int sc4  = lane & 3;

    float4 hreg[4], wreg[4];

    // ---- prologue: chunk 0
#pragma unroll
    for (int p = 0; p < 4; ++p) {
        hreg[p] = *reinterpret_cast<const float4*>(
            &hidden[(tokBase + p * 16 + srow) * HDIM + kw + sc4 * 4]);
        wreg[p] = *reinterpret_cast<const float4*>(
            &wgate[(size_t)(p * 16 + srow) * HDIM + kw + sc4 * 4]);
    }
#pragma unroll
    for (int p = 0; p < 4; ++p) {
        *reinterpret_cast<float4*>(&Ht[(p * 16 + srow) * TROW + sc4 * 4]) = hreg[p];
        *reinterpret_cast<float4*>(&Wt[(p * 16 + srow) * TROW + sc4 * 4]) = wreg[p];
    }

    for (int c = 0; c < NCH; ++c) {
        // issue next chunk's global loads early (land under ~2000cy of FMA)
        if (c + 1 < NCH) {
            const int kn = kw + (c + 1) * BK;
#pragma unroll
            for (int p = 0; p < 4; ++p) {
                hreg[p] = *reinterpret_cast<const float4*>(
                    &hidden[(tokBase + p * 16 + srow) * HDIM + kn + sc4 * 4]);
                wreg[p] = *reinterpret_cast<const float4*>(
                    &wgate[(size_t)(p * 16 + srow) * HDIM + kn + sc4 * 4]);
            }
        }

        // compute chunk c: 4 k4-steps; per step 8 H-reads + 2x4 W-reads,
        // each set hits all 32 banks exactly once (pad 20), 8-way broadcast.
#pragma unroll
        for (int kk = 0; kk < BK; kk += 4) {
            float4 h4[8];
#pragma unroll
            for (int i = 0; i < 8; ++i)
                h4[i] = *reinterpret_cast<const float4*>(&Ht[(tg + 8 * i) * TROW + kk]);
            float4 w4[4];
#pragma unroll
            for (int j = 0; j < 4; ++j)
                w4[j] = *reinterpret_cast<const float4*>(&Wt[(eg + 8 * j) * TROW + kk]);
#pragma unroll
            for (int i = 0; i < 8; ++i)
#pragma unroll
                for (int j = 0; j < 4; ++j) {
                    acc[i][j] += h4[i].x * w4[j].x;
                    acc[i][j] += h4[i].y * w4[j].y;
                    acc[i][j] += h4[i].z * w4[j].z;
                    acc[i][j] += h4[i].w * w4[j].w;
                }
#pragma unroll
            for (int j = 0; j < 4; ++j)
                w4[j] = *reinterpret_cast<const float4*>(&Wt[(eg + 32 + 8 * j) * TROW + kk]);
#pragma unroll
            for (int i = 0; i < 8; ++i)
#pragma unroll
                for (int j = 0; j < 4; ++j) {
                    acc[i][j + 4] += h4[i].x * w4[j].x;
                    acc[i][j + 4] += h4[i].y * w4[j].y;
                    acc[i][j + 4] += h4[i].z * w4[j].z;
                    acc[i][j + 4] += h4[i].w * w4[j].w;
                }
        }

        // write staged chunk c+1 (same wave: DS ops ordered after the reads)
        if (c + 1 < NCH) {
#pragma unroll
            for (int p = 0; p < 4; ++p) {
                *reinterpret_cast<float4*>(&Ht[(p * 16 + srow) * TROW + sc4 * 4]) = hreg[p];
                *reinterpret_cast<float4*>(&Wt[(p * 16 + srow) * TROW + sc4 * 4]) = wreg[p];
            }
        }
    }

    // ---- tree-reduce 8 k-partials into wave 0 (reuse lds) ----
    // acc[i][j] holds token tg+8i, expert eg+8j (note: j split above maps
    // acc[i][j] -> expert eg+8j for j<4 and eg+32+8*(j-4) for j>=4).
    // Unify the expert index helper:
    //   ecol(j) = (j < 4) ? eg + 8*j : eg + 32 + 8*(j-4)
    __syncthreads();
    if (wv >= 4) {
        float* R = &lds[(wv - 4) * RSL];
#pragma unroll
        for (int i = 0; i < 8; ++i)
#pragma unroll
            for (int j = 0; j < 8; ++j) {
                const int ec = (j < 4) ? (eg + 8 * j) : (eg + 32 + 8 * (j - 4));
                R[(tg + 8 * i) * RROW + ec] = acc[i][j];
            }
    }
    __syncthreads();
    if (wv < 4) {
        const float* R = &lds[wv * RSL];
#pragma unroll
        for (int i = 0; i < 8; ++i)
#pragma unroll
            for (int j = 0; j < 8; ++j) {
                const int ec = (j < 4) ? (eg + 8 * j) : (eg + 32 + 8 * (j - 4));
                acc[i][j] += R[(tg + 8 * i) * RROW + ec];
            }
    }
    __syncthreads();
    if (wv == 2 || wv == 3) {
        float* R = &lds[(wv - 2) * RSL];
#pragma unroll
        for (int i = 0; i < 8; ++i)
#pragma unroll
            for (int j = 0; j < 8; ++j) {
                const int ec = (j < 4) ? (eg + 8 * j) : (eg + 32 + 8 * (j - 4));
                R[(tg + 8 * i) * RROW + ec] = acc[i][j];
            }
    }
    __syncthreads();
    if (wv < 2) {
        const float* R = &lds[wv * RSL];
#pragma unroll
        for (int i = 0; i < 8; ++i)
#pragma unroll
            for (int j = 0; j < 8; ++j) {
                const int ec = (j < 4) ? (eg + 8 * j) : (eg + 32 + 8 * (j - 4));
                acc[i][j] += R[(tg + 8 * i) * RROW + ec];
            }
    }
    __syncthreads();
    if (wv == 1) {
        float* R = &lds[0];
#pragma unroll
        for (int i = 0; i < 8; ++i)
#pragma unroll
            for (int j = 0; j < 8; ++j) {
                const int ec = (j < 4) ? (eg + 8 * j) : (eg + 32 + 8 * (j - 4));
                R[(tg + 8 * i) * RROW + ec] = acc[i][j];
            }
    }
    __syncthreads();
    if (wv == 0) {
        float* R = &lds[0];
#pragma unroll
        for (int i = 0; i < 8; ++i)
#pragma unroll
            for (int j = 0; j < 8; ++j) {
                const int ec = (j < 4) ? (eg + 8 * j) : (eg + 32 + 8 * (j - 4));
                const float v = acc[i][j] + R[(tg + 8 * i) * RROW + ec];
                R[(tg + 8 * i) * RROW + ec] = v;   // final tile
            }
    }
    __syncthreads();

    // ---- fused epilogue ----
    if (wv == 0) {
        // coalesced logits store: 16 instrs x (4 rows x 16 lanes x 16B)
#pragma unroll
        for (int p = 0; p < 16; ++p) {
            const int row = p * 4 + (lane >> 4);
            const int col = 4 * (lane & 15);
            const float4 v4 = *reinterpret_cast<const float4*>(&lds[row * RROW + col]);
            *reinterpret_cast<float4*>(&logits[(tokBase + row) * NEXP + col]) = v4;
        }
    } else if (wv == 1) {
        // top-9 scan, lane = token
        const int t = lane;
        float v[NEXP];
#pragma unroll
        for (int q = 0; q < 16; ++q) {
            const float4 f = *reinterpret_cast<const float4*>(&lds[t * RROW + 4 * q]);
            v[4 * q + 0] = f.x; v[4 * q + 1] = f.y;
            v[4 * q + 2] = f.z; v[4 * q + 3] = f.w;
        }

        float bv[NSCAN];
        int   bidx[NSCAN];
        unsigned long long used = 0ull;
#pragma unroll
        for (int k = 0; k < NSCAN; ++k) {
            float best = -INFINITY;
            int   bi   = 0;
#pragma unroll
            for (int i = 0; i < NEXP; ++i) {
                const bool avail = ((used >> i) & 1ull) == 0ull;
                if (avail && v[i] > best) { best = v[i]; bi = i; }
            }
            bv[k]   = best;
            bidx[k] = bi;
            used |= (1ull << bi);
        }

        float ming = bv[0] - bv[1];
#pragma unroll
        for (int k = 1; k < NSCAN - 1; ++k) ming = fminf(ming, bv[k] - bv[k + 1]);
        const size_t gt = tokBase + t;
        if (ming < TAU) {
            const int pos = atomicAdd(cnt, 1);   // order-free: fixup is per-token
            list[pos] = (int)gt;
        }

        const float m = bv[0];
        float ek[TOPK];
        float s = 0.f;
#pragma unroll
        for (int k = 0; k < TOPK; ++k) { ek[k] = expf(bv[k] - m); s += ek[k]; }
        const float inv = 1.0f / s;
#pragma unroll
        for (int k = 0; k < TOPK; ++k) {
            selw[gt * TOPK + k]   = ek[k] * inv;
            selidx[gt * TOPK + k] = (float)bidx[k];
        }
    }
}

// ---------------- fp64 re-dot + exact top-8 for flagged tokens ------------
__global__ __launch_bounds__(256) void gate_fixup_f64(
    const float* __restrict__ hidden,
    const float* __restrict__ wgate,
    const int* __restrict__ cnt,
    const int* __restrict__ list,
    float* __restrict__ selw,
    float* __restrict__ selidx)
{
    const int lane   = threadIdx.x & 63;
    const int waveId = (blockIdx.x * blockDim.x + threadIdx.x) >> 6;
    const int nWaves = (gridDim.x * blockDim.x) >> 6;
    const int n      = *cnt;

    for (int i = waveId; i < n; i += nWaves) {
        const int t = list[i];
        const float* hrow = &hidden[(size_t)t * HDIM];
        const float* wrow = &wgate[(size_t)lane * HDIM];

        double a0 = 0.0, a1 = 0.0, a2 = 0.0, a3 = 0.0;
#pragma unroll 2
        for (int k = 0; k < HDIM; k += 16) {
            const float4 h0 = *reinterpret_cast<const float4*>(&hrow[k +  0]);
            const float4 h1 = *reinterpret_cast<const float4*>(&hrow[k +  4]);
            const float4 h2 = *reinterpret_cast<const float4*>(&hrow[k +  8]);
            const float4 h3 = *reinterpret_cast<const float4*>(&hrow[k + 12]);
            const float4 w0 = *reinterpret_cast<const float4*>(&wrow[k +  0]);
            const float4 w1 = *reinterpret_cast<const float4*>(&wrow[k +  4]);
            const float4 w2 = *reinterpret_cast<const float4*>(&wrow[k +  8]);
            const float4 w3 = *reinterpret_cast<const float4*>(&wrow[k + 12]);
            a0 += (double)h0.x * w0.x + (double)h0.y * w0.y
                + (double)h0.z * w0.z + (double)h0.w * w0.w;
            a1 += (double)h1.x * w1.x + (double)h1.y * w1.y
                + (double)h1.z * w1.z + (double)h1.w * w1.w;
            a2 += (double)h2.x * w2.x + (double)h2.y * w2.y
                + (double)h2.z * w2.z + (double)h2.w * w2.w;
            a3 += (double)h3.x * w3.x + (double)h3.y * w3.y
                + (double)h3.z * w3.z + (double)h3.w * w3.w;
        }
        double v = (a0 + a1) + (a2 + a3);
        int   id = lane;

        double bv[TOPK];
        int    bidx[TOPK];
#pragma unroll
        for (int p = 0; p < TOPK; ++p) {
            double mv = v;
            int    mi = id;
#pragma unroll
            for (int off = 32; off >= 1; off >>= 1) {
                const double ov = __shfl_xor(mv, off);
                const int    oi = __shfl_xor(mi, off);
                if (ov > mv || (ov == mv && oi < mi)) { mv = ov; mi = oi; }
            }
            bv[p]   = mv;
            bidx[p] = mi;
            if (id == mi) v = -INFINITY;
        }

        if (lane == 0) {
            float ek[TOPK];
            float s = 0.f;
#pragma unroll
            for (int p = 0; p < TOPK; ++p) {
                ek[p] = expf((float)(bv[p] - bv[0]));
                s += ek[p];
            }
            const float inv = 1.0f / s;
#pragma unroll
            for (int p = 0; p < TOPK; ++p) {
                selw[(size_t)t * TOPK + p]   = ek[p] * inv;
                selidx[(size_t)t * TOPK + p] = (float)bidx[p];
            }
        }
    }
}

extern "C" void kernel_launch(void* const* d_in, const int* in_sizes, int n_in,
                              void* d_out, int out_size, void* d_ws, size_t ws_size,
                              hipStream_t stream) {
    const float* hidden = (const float*)d_in[0];   // [4,4096,2048] f32
    const float* wgate  = (const float*)d_in[1];   // [64,2048] f32

    const int T = in_sizes[0] / HDIM;              // 16384 tokens

    float* out    = (float*)d_out;
    float* selw   = out;                           // T*8
    float* selidx = out + (size_t)T * TOPK;        // T*8
    float* logits = out + (size_t)2 * T * TOPK;    // T*64

    int* cnt  = (int*)d_ws;
    int* list = (int*)d_ws + 64;

    hipMemsetAsync(d_ws, 0, 256, stream);

    gate_fused<<<T / 64, 512, 0, stream>>>(hidden, wgate, logits,
                                           selw, selidx, cnt, list);
    gate_fixup_f64<<<256, 256, 0, stream>>>(hidden, wgate, cnt, list, selw, selidx);
}

// Round 7
// 159.915 us; speedup vs baseline: 3.3739x; 3.3739x over previous
//
#include <hip/hip_runtime.h>
#include <math.h>

// Qwen3 MoE gate: logits = hidden @ W_gate^T ; softmax ; top-8 ; renorm.
// Outputs (flat f32): sel_w [T*8], sel_idx-as-float [T*8], logits [T*64].
//
// R7: kill the spill (R5/R6: VGPR pinned at 128, ~1GB scratch WRITE_SIZE).
//  - staging regs eliminated: global_load_lds (width 16) into per-wave
//    double-buffered LINEAR [64][8] tiles; XOR swizzle c4^= (row&1) applied
//    on BOTH global source and LDS read (G21 involution) -> compute reads
//    are 16 banks x 2-way = free (m136).
//  - #pragma unroll 1 on the chunk loop (R6's full unroll + pipelining is
//    the suspected pressure source); W fragments in two halves of 4.
//    Steady live set ~124 VGPR <= 128.
//  - structure otherwise = R6: 8x8 thread tile, 8-way k-split, zero k-loop
//    barriers, LDS tree-reduce, fused logits/top-9/flag epilogue, fp64
//    fixup pass for near-tie tokens.

#define HDIM 2048
#define NEXP 64
#define TOPK 8
#define NSCAN 9
#define TAU  2.5e-4f

#define KSPLIT 8
#define KWIN  (HDIM / KSPLIT)   // 256 k per wave
#define BK    8                 // k per staged chunk
#define NCH   (KWIN / BK)       // 32 chunks
#define TILEF 512               // floats per tile: 64 rows x 8
#define WVF   2048              // floats per wave: 2 bufs x (H 512 + W 512)
#define RROW  68                // reduce row stride (floats)
#define RSL   (64 * RROW)       // 4352 floats per reduce slice

__global__ __launch_bounds__(512, 1) void gate_fused(
    const float* __restrict__ hidden,   // [T, 2048]
    const float* __restrict__ wgate,    // [64, 2048]
    float* __restrict__ logits,         // [T, 64]
    float* __restrict__ selw,           // [T, 8]
    float* __restrict__ selidx,         // [T, 8]
    int* __restrict__ cnt,
    int* __restrict__ list)
{
    __shared__ float lds[4 * RSL];      // 17408 floats = 68 KiB >= 8*WVF=16384

    const int tid  = threadIdx.x;
    const int lane = tid & 63;
    const int wv   = __builtin_amdgcn_readfirstlane(tid >> 6);
    const int tg   = lane & 7;     // token group: tokens tg + 8i
    const int eg   = lane >> 3;    // expert group: experts eg+8j / eg+32+8j
    const size_t tokBase = (size_t)blockIdx.x * 64;
    const int kw   = wv * KWIN;

    float* wbase = &lds[wv * WVF];      // wave-uniform (wv is SGPR)

    float acc[8][8];
#pragma unroll
    for (int i = 0; i < 8; ++i)
#pragma unroll
        for (int j = 0; j < 8; ++j) acc[i][j] = 0.f;

    // ---- async staging: 2 gload_lds per tile (128 f4 per tile).
    // f4 index f = p*64+lane; row = f>>1; c4 = f&1; source col = c4^(row&1).
    // LDS dest is linear (base + lane*16B) — swizzle lives in the source.
    const int srow0 = lane >> 1;                    // p=0 rows 0..31
    const int sc40  = (lane & 1) ^ (srow0 & 1);
    const int srow1 = (64 + lane) >> 1;             // p=1 rows 32..63
    const int sc41  = (lane & 1) ^ (srow1 & 1);

    auto stage = [&](int b, int c) {
        const int kc = kw + c * BK;
        float* Hb = wbase + b * 1024;
        float* Wb = Hb + TILEF;
        __builtin_amdgcn_global_load_lds(
            (const __attribute__((address_space(1))) void*)
                &hidden[(tokBase + srow0) * HDIM + kc + sc40 * 4],
            (__attribute__((address_space(3))) void*)(Hb), 16, 0, 0);
        __builtin_amdgcn_global_load_lds(
            (const __attribute__((address_space(1))) void*)
                &hidden[(tokBase + srow1) * HDIM + kc + sc41 * 4],
            (__attribute__((address_space(3))) void*)(Hb + 256), 16, 0, 0);
        __builtin_amdgcn_global_load_lds(
            (const __attribute__((address_space(1))) void*)
                &wgate[(size_t)srow0 * HDIM + kc + sc40 * 4],
            (__attribute__((address_space(3))) void*)(Wb), 16, 0, 0);
        __builtin_amdgcn_global_load_lds(
            (const __attribute__((address_space(1))) void*)
                &wgate[(size_t)srow1 * HDIM + kc + sc41 * 4],
            (__attribute__((address_space(3))) void*)(Wb + 256), 16, 0, 0);
    };

    stage(0, 0);
    asm volatile("s_waitcnt vmcnt(0)" ::: "memory");

    // read-side swizzle: slot toggle is (row&1) = (tg&1) for H, (eg&1) for W
    const int hx = tg & 1;
    const int wx = eg & 1;

    int buf = 0;
#pragma unroll 1
    for (int c = 0; c < NCH; ++c) {
        if (c + 1 < NCH) stage(buf ^ 1, c + 1);

        const float* Hb = wbase + buf * 1024;
        const float* Wb = Hb + TILEF;
#pragma unroll
        for (int kk = 0; kk < 2; ++kk) {            // two k4-steps (q = kk)
            float4 h4[8];
#pragma unroll
            for (int i = 0; i < 8; ++i)
                h4[i] = *reinterpret_cast<const float4*>(
                    &Hb[(tg + 8 * i) * 8 + ((kk ^ hx) * 4)]);
            float4 w4[4];
#pragma unroll
            for (int j = 0; j < 4; ++j)
                w4[j] = *reinterpret_cast<const float4*>(
                    &Wb[(eg + 8 * j) * 8 + ((kk ^ wx) * 4)]);
#pragma unroll
            for (int i = 0; i < 8; ++i)
#pragma unroll
                for (int j = 0; j < 4; ++j) {
                    acc[i][j] += h4[i].x * w4[j].x;
                    acc[i][j] += h4[i].y * w4[j].y;
                    acc[i][j] += h4[i].z * w4[j].z;
                    acc[i][j] += h4[i].w * w4[j].w;
                }
#pragma unroll
            for (int j = 0; j < 4; ++j)
                w4[j] = *reinterpret_cast<const float4*>(
                    &Wb[(eg + 32 + 8 * j) * 8 + ((kk ^ wx) * 4)]);
#pragma unroll
            for (int i = 0; i < 8; ++i)
#pragma unroll
                for (int j = 0; j < 4; ++j) {
                    acc[i][j + 4] += h4[i].x * w4[j].x;
                    acc[i][j + 4] += h4[i].y * w4[j].y;
                    acc[i][j + 4] += h4[i].z * w4[j].z;
                    acc[i][j + 4] += h4[i].w * w4[j].w;
                }
        }

        if (c + 1 < NCH)
            asm volatile("s_waitcnt vmcnt(0)" ::: "memory");
        buf ^= 1;
    }

    // ---- tree-reduce 8 k-partials into wave 0 (reuse lds) ----
    // acc[i][j]: token tg+8i, expert ec(j) = j<4 ? eg+8j : eg+32+8(j-4)
    __syncthreads();
    if (wv >= 4) {
        float* R = &lds[(wv - 4) * RSL];
#pragma unroll
        for (int i = 0; i < 8; ++i)
#pragma unroll
            for (int j = 0; j < 8; ++j) {
                const int ec = (j < 4) ? (eg + 8 * j) : (eg + 32 + 8 * (j - 4));
                R[(tg + 8 * i) * RROW + ec] = acc[i][j];
            }
    }
    __syncthreads();
    if (wv < 4) {
        const float* R = &lds[wv * RSL];
#pragma unroll
        for (int i = 0; i < 8; ++i)
#pragma unroll
            for (int j = 0; j < 8; ++j) {
                const int ec = (j < 4) ? (eg + 8 * j) : (eg + 32 + 8 * (j - 4));
                acc[i][j] += R[(tg + 8 * i) * RROW + ec];
            }
    }
    __syncthreads();
    if (wv == 2 || wv == 3) {
        float* R = &lds[(wv - 2) * RSL];
#pragma unroll
        for (int i = 0; i < 8; ++i)
#pragma unroll
            for (int j = 0; j < 8; ++j) {
                const int ec = (j < 4) ? (eg + 8 * j) : (eg + 32 + 8 * (j - 4));
                R[(tg + 8 * i) * RROW + ec] = acc[i][j];
            }
    }
    __syncthreads();
    if (wv < 2) {
        const float* R = &lds[wv * RSL];
#pragma unroll
        for (int i = 0; i < 8; ++i)
#pragma unroll
            for (int j = 0; j < 8; ++j) {
                const int ec = (j < 4) ? (eg + 8 * j) : (eg + 32 + 8 * (j - 4));
                acc[i][j] += R[(tg + 8 * i) * RROW + ec];
            }
    }
    __syncthreads();
    if (wv == 1) {
        float* R = &lds[0];
#pragma unroll
        for (int i = 0; i < 8; ++i)
#pragma unroll
            for (int j = 0; j < 8; ++j) {
                const int ec = (j < 4) ? (eg + 8 * j) : (eg + 32 + 8 * (j - 4));
                R[(tg + 8 * i) * RROW + ec] = acc[i][j];
            }
    }
    __syncthreads();
    if (wv == 0) {
        float* R = &lds[0];
#pragma unroll
        for (int i = 0; i < 8; ++i)
#pragma unroll
            for (int j = 0; j < 8; ++j) {
                const int ec = (j < 4) ? (eg + 8 * j) : (eg + 32 + 8 * (j - 4));
                const float v = acc[i][j] + R[(tg + 8 * i) * RROW + ec];
                R[(tg + 8 * i) * RROW + ec] = v;   // final tile
            }
    }
    __syncthreads();

    // ---- fused epilogue ----
    if (wv == 0) {
        // coalesced logits store: 16 instrs x (4 rows x 16 lanes x 16B)
#pragma unroll
        for (int p = 0; p < 16; ++p) {
            const int row = p * 4 + (lane >> 4);
            const int col = 4 * (lane & 15);
            const float4 v4 = *reinterpret_cast<const float4*>(&lds[row * RROW + col]);
            *reinterpret_cast<float4*>(&logits[(tokBase + row) * NEXP + col]) = v4;
        }
    } else if (wv == 1) {
        // top-9 scan, lane = token
        const int t = lane;
        float v[NEXP];
#pragma unroll
        for (int q = 0; q < 16; ++q) {
            const float4 f = *reinterpret_cast<const float4*>(&lds[t * RROW + 4 * q]);
            v[4 * q + 0] = f.x; v[4 * q + 1] = f.y;
            v[4 * q + 2] = f.z; v[4 * q + 3] = f.w;
        }

        float bv[NSCAN];
        int   bidx[NSCAN];
        unsigned long long used = 0ull;
#pragma unroll
        for (int k = 0; k < NSCAN; ++k) {
            float best = -INFINITY;
            int   bi   = 0;
#pragma unroll
            for (int i = 0; i < NEXP; ++i) {
                const bool avail = ((used >> i) & 1ull) == 0ull;
                if (avail && v[i] > best) { best = v[i]; bi = i; }
            }
            bv[k]   = best;
            bidx[k] = bi;
            used |= (1ull << bi);
        }

        float ming = bv[0] - bv[1];
#pragma unroll
        for (int k = 1; k < NSCAN - 1; ++k) ming = fminf(ming, bv[k] - bv[k + 1]);
        const size_t gt = tokBase + t;
        if (ming < TAU) {
            const int pos = atomicAdd(cnt, 1);   // order-free: fixup is per-token
            list[pos] = (int)gt;
        }

        const float m = bv[0];
        float ek[TOPK];
        float s = 0.f;
#pragma unroll
        for (int k = 0; k < TOPK; ++k) { ek[k] = expf(bv[k] - m); s += ek[k]; }
        const float inv = 1.0f / s;
#pragma unroll
        for (int k = 0; k < TOPK; ++k) {
            selw[gt * TOPK + k]   = ek[k] * inv;
            selidx[gt * TOPK + k] = (float)bidx[k];
        }
    }
}

// ---------------- fp64 re-dot + exact top-8 for flagged tokens ------------
__global__ __launch_bounds__(256) void gate_fixup_f64(
    const float* __restrict__ hidden,
    const float* __restrict__ wgate,
    const int* __restrict__ cnt,
    const int* __restrict__ list,
    float* __restrict__ selw,
    float* __restrict__ selidx)
{
    const int lane   = threadIdx.x & 63;
    const int waveId = (blockIdx.x * blockDim.x + threadIdx.x) >> 6;
    const int nWaves = (gridDim.x * blockDim.x) >> 6;
    const int n      = *cnt;

    for (int i = waveId; i < n; i += nWaves) {
        const int t = list[i];
        const float* hrow = &hidden[(size_t)t * HDIM];
        const float* wrow = &wgate[(size_t)lane * HDIM];

        double a0 = 0.0, a1 = 0.0, a2 = 0.0, a3 = 0.0;
#pragma unroll 2
        for (int k = 0; k < HDIM; k += 16) {
            const float4 h0 = *reinterpret_cast<const float4*>(&hrow[k +  0]);
            const float4 h1 = *reinterpret_cast<const float4*>(&hrow[k +  4]);
            const float4 h2 = *reinterpret_cast<const float4*>(&hrow[k +  8]);
            const float4 h3 = *reinterpret_cast<const float4*>(&hrow[k + 12]);
            const float4 w0 = *reinterpret_cast<const float4*>(&wrow[k +  0]);
            const float4 w1 = *reinterpret_cast<const float4*>(&wrow[k +  4]);
            const float4 w2 = *reinterpret_cast<const float4*>(&wrow[k +  8]);
            const float4 w3 = *reinterpret_cast<const float4*>(&wrow[k + 12]);
            a0 += (double)h0.x * w0.x + (double)h0.y * w0.y
                + (double)h0.z * w0.z + (double)h0.w * w0.w;
            a1 += (double)h1.x * w1.x + (double)h1.y * w1.y
                + (double)h1.z * w1.z + (double)h1.w * w1.w;
            a2 += (double)h2.x * w2.x + (double)h2.y * w2.y
                + (double)h2.z * w2.z + (double)h2.w * w2.w;
            a3 += (double)h3.x * w3.x + (double)h3.y * w3.y
                + (double)h3.z * w3.z + (double)h3.w * w3.w;
        }
        double v = (a0 + a1) + (a2 + a3);
        int   id = lane;

        double bv[TOPK];
        int    bidx[TOPK];
#pragma unroll
        for (int p = 0; p < TOPK; ++p) {
            double mv = v;
            int    mi = id;
#pragma unroll
            for (int off = 32; off >= 1; off >>= 1) {
                const double ov = __shfl_xor(mv, off);
                const int    oi = __shfl_xor(mi, off);
                if (ov > mv || (ov == mv && oi < mi)) { mv = ov; mi = oi; }
            }
            bv[p]   = mv;
            bidx[p] = mi;
            if (id == mi) v = -INFINITY;
        }

        if (lane == 0) {
            float ek[TOPK];
            float s = 0.f;
#pragma unroll
            for (int p = 0; p < TOPK; ++p) {
                ek[p] = expf((float)(bv[p] - bv[0]));
                s += ek[p];
            }
            const float inv = 1.0f / s;
#pragma unroll
            for (int p = 0; p < TOPK; ++p) {
                selw[(size_t)t * TOPK + p]   = ek[p] * inv;
                selidx[(size_t)t * TOPK + p] = (float)bidx[p];
            }
        }
    }
}

extern "C" void kernel_launch(void* const* d_in, const int* in_sizes, int n_in,
                              void* d_out, int out_size, void* d_ws, size_t ws_size,
                              hipStream_t stream) {
    const float* hidden = (const float*)d_in[0];   // [4,4096,2048] f32
    const float* wgate  = (const float*)d_in[1];   // [64,2048] f32

    const int T = in_sizes[0] / HDIM;              // 16384 tokens

    float* out    = (float*)d_out;
    float* selw   = out;                           // T*8
    float* selidx = out + (size_t)T * TOPK;        // T*8
    float* logits = out + (size_t)2 * T * TOPK;    // T*64

    int* cnt  = (int*)d_ws;
    int* list = (int*)d_ws + 64;

    hipMemsetAsync(d_ws, 0, 256, stream);

    gate_fused<<<T / 64, 512, 0, stream>>>(hidden, wgate, logits,
                                           selw, selidx, cnt, list);
    gate_fixup_f64<<<256, 256, 0, stream>>>(hidden, wgate, cnt, list, selw, selidx);
}

// Round 8
// 90.354 us; speedup vs baseline: 5.9713x; 1.7699x over previous
//
#include <hip/hip_runtime.h>
#include <math.h>

// Qwen3 MoE gate: logits = hidden @ W_gate^T ; softmax ; top-8 ; renorm.
// Outputs (flat f32): sel_w [T*8], sel_idx-as-float [T*8], logits [T*64].
//
// R8: bf16-split MFMA (Markidis 3-term: hi*hi + hi*lo + lo*hi) — moves the
// GEMM from the 157TF fp32 VALU (R7: LDS-pipe-bound at 99us) to the 2.5PF
// matrix pipe; logit noise ~1.5e-5 << TAU=2.5e-4, so the near-tie flag +
// fp64 fixup correctness scheme is unchanged.
//  - prep kernel: W (512KB) -> fragment-ordered bf16 hi/lo records in d_ws
//    (L2-resident; in-kernel W = coalesced 1KB global b128 reads, no LDS).
//  - main: mfma_f32_32x32x16_bf16; wave = 32 tok x 64 exp; 4-way k-split;
//    H via gload_lds chunk-XOR-swizzled per-wave tiles; in-reg cvt_pk split
//    (H and W packed identically -> k-permutation cancels in the dot).
//  - fixup: 1 block per flagged token, 4-wave k-split (R7's was 1 wave/token
//    with serial k=2048 -> ~55us wall; this -> ~5us).

#define HDIM 2048
#define NEXP 64
#define TOPK 8
#define NSCAN 9
#define TAU  2.5e-4f

typedef __attribute__((ext_vector_type(8)))  short short8;
typedef __attribute__((ext_vector_type(16))) float f32x16;

__device__ __forceinline__ unsigned cvtpk(float a, float b) {
    unsigned r;
    asm("v_cvt_pk_bf16_f32 %0, %1, %2" : "=v"(r) : "v"(a), "v"(b));
    return r;  // [15:0]=bf16(a), [31:16]=bf16(b)
}

// split 8 fp32 -> hi/lo bf16 fragments (4 packed u32 each); exact: h=hi+lo
__device__ __forceinline__ void split8(const float* h, uint4& hi, uint4& lo) {
    const unsigned h0 = cvtpk(h[0], h[1]);
    const unsigned h1 = cvtpk(h[2], h[3]);
    const unsigned h2 = cvtpk(h[4], h[5]);
    const unsigned h3 = cvtpk(h[6], h[7]);
    const float l0 = h[0] - __uint_as_float(h0 << 16);
    const float l1 = h[1] - __uint_as_float(h0 & 0xFFFF0000u);
    const float l2 = h[2] - __uint_as_float(h1 << 16);
    const float l3 = h[3] - __uint_as_float(h1 & 0xFFFF0000u);
    const float l4 = h[4] - __uint_as_float(h2 << 16);
    const float l5 = h[5] - __uint_as_float(h2 & 0xFFFF0000u);
    const float l6 = h[6] - __uint_as_float(h3 << 16);
    const float l7 = h[7] - __uint_as_float(h3 & 0xFFFF0000u);
    hi = make_uint4(h0, h1, h2, h3);
    lo = make_uint4(cvtpk(l0, l1), cvtpk(l2, l3), cvtpk(l4, l5), cvtpk(l6, l7));
}

// ---- prep: W[64][2048] f32 -> frag-ordered bf16 hi/lo records ------------
// record rec = (kb*2 + j)*2 + s  (kb = k/16, j = expert-tile, s = hi/lo),
// 64 lanes x 16B: lane holds W[j*32 + (lane&31)][kb*16 + (lane>>5)*8 + 0..7]
// == the exact B-operand layout of mfma_f32_32x32x16_bf16.
__global__ __launch_bounds__(128) void prep_wfrag(
    const float* __restrict__ wgate, uint4* __restrict__ wf)
{
    const int g    = blockIdx.x * 128 + threadIdx.x;  // 16384 = 128kb*2j*64lane
    const int kb   = g >> 7;
    const int j    = (g >> 6) & 1;
    const int lane = g & 63;
    const int row  = j * 32 + (lane & 31);
    const int kofs = kb * 16 + (lane >> 5) * 8;
    const float4 a = *reinterpret_cast<const float4*>(&wgate[row * HDIM + kofs]);
    const float4 b = *reinterpret_cast<const float4*>(&wgate[row * HDIM + kofs + 4]);
    const float h[8] = {a.x, a.y, a.z, a.w, b.x, b.y, b.z, b.w};
    uint4 hi, lo;
    split8(h, hi, lo);
    wf[(((kb * 2 + j) * 2) + 0) * 64 + lane] = hi;
    wf[(((kb * 2 + j) * 2) + 1) * 64 + lane] = lo;
}

// ---- main: GEMM(MFMA) + fused top-9/flag epilogue -------------------------
__global__ __launch_bounds__(256, 2) void gate_fused(
    const float* __restrict__ hidden,   // [T, 2048]
    const uint4* __restrict__ wf,       // frag records
    float* __restrict__ logits,
    float* __restrict__ selw,
    float* __restrict__ selidx,
    int* __restrict__ cnt,
    int* __restrict__ list)
{
    __shared__ float lds[8192];         // 32 KiB: 4 waves x dbuf x 1024 f
    const int tid  = threadIdx.x;
    const int lane = tid & 63;
    const int wv   = __builtin_amdgcn_readfirstlane(tid >> 6);  // 0..3
    const size_t tokBase = (size_t)blockIdx.x * 32;
    const int kw   = wv * 512;          // this wave's k-window

    float* Hbuf = &lds[wv * 2048];

    f32x16 acc0 = {0,0,0,0,0,0,0,0,0,0,0,0,0,0,0,0};
    f32x16 acc1 = {0,0,0,0,0,0,0,0,0,0,0,0,0,0,0,0};

    // stage one 32tok x 32k chunk: linear LDS dest, chunk-XOR swizzle on the
    // global source (G21); read applies the same XOR -> uniform bank load.
    auto stage = [&](int b, int kc) {
#pragma unroll
        for (int p = 0; p < 4; ++p) {
            const int row = p * 8 + (lane >> 3);
            const int sc  = (lane & 7) ^ (row & 7);
            __builtin_amdgcn_global_load_lds(
                (const __attribute__((address_space(1))) void*)
                    &hidden[(tokBase + row) * HDIM + kc + sc * 4],
                (__attribute__((address_space(3))) void*)(Hbuf + b * 1024 + p * 256),
                16, 0, 0);
        }
    };

    stage(0, kw);
    asm volatile("s_waitcnt vmcnt(0)" ::: "memory");

    int buf = 0;
#pragma unroll 1
    for (int c = 0; c < 16; ++c) {
        if (c + 1 < 16) stage(buf ^ 1, kw + (c + 1) * 32);
        const float* Hb = Hbuf + buf * 1024;
#pragma unroll
        for (int st = 0; st < 2; ++st) {
            const int kb = wv * 32 + c * 2 + st;
            // B-operand fragments straight from L2 (coalesced 1KB/instr)
            const uint4 wh0 = wf[((kb * 2 + 0) * 2 + 0) * 64 + lane];
            const uint4 wl0 = wf[((kb * 2 + 0) * 2 + 1) * 64 + lane];
            const uint4 wh1 = wf[((kb * 2 + 1) * 2 + 0) * 64 + lane];
            const uint4 wl1 = wf[((kb * 2 + 1) * 2 + 1) * 64 + lane];
            // A-operand: 8 fp32 of own token-row from LDS (logical chunk
            // cch, stored at cch^(row&7))
            const int row = lane & 31;
            const int cch = st * 4 + (lane >> 5) * 2;
            const float4 ha = *reinterpret_cast<const float4*>(
                &Hb[row * 32 + ((cch)     ^ (row & 7)) * 4]);
            const float4 hb = *reinterpret_cast<const float4*>(
                &Hb[row * 32 + ((cch + 1) ^ (row & 7)) * 4]);
            const float h[8] = {ha.x, ha.y, ha.z, ha.w, hb.x, hb.y, hb.z, hb.w};
            uint4 hhi, hlo;
            split8(h, hhi, hlo);
            const short8 Ahi = __builtin_bit_cast(short8, hhi);
            const short8 Alo = __builtin_bit_cast(short8, hlo);
            acc0 = __builtin_amdgcn_mfma_f32_32x32x16_bf16(Ahi, __builtin_bit_cast(short8, wh0), acc0, 0, 0, 0);
            acc1 = __builtin_amdgcn_mfma_f32_32x32x16_bf16(Ahi, __builtin_bit_cast(short8, wh1), acc1, 0, 0, 0);
            acc0 = __builtin_amdgcn_mfma_f32_32x32x16_bf16(Ahi, __builtin_bit_cast(short8, wl0), acc0, 0, 0, 0);
            acc1 = __builtin_amdgcn_mfma_f32_32x32x16_bf16(Ahi, __builtin_bit_cast(short8, wl1), acc1, 0, 0, 0);
            acc0 = __builtin_amdgcn_mfma_f32_32x32x16_bf16(Alo, __builtin_bit_cast(short8, wh0), acc0, 0, 0, 0);
            acc1 = __builtin_amdgcn_mfma_f32_32x32x16_bf16(Alo, __builtin_bit_cast(short8, wh1), acc1, 0, 0, 0);
        }
        asm volatile("s_waitcnt vmcnt(0)" ::: "memory");
        buf ^= 1;
    }

    // ---- reduce 4 k-partials (C/D layout: col=lane&31, row=(r&3)+8*(r>>2)
    // +4*(lane>>5)), then fused epilogue ----
    __syncthreads();
    float* S0 = &lds[0];
    float* S1 = &lds[4096];
    if (wv >= 2) {
        float* S = (wv == 2) ? S0 : S1;
#pragma unroll
        for (int r = 0; r < 16; ++r) {
            const int row = (r & 3) + 8 * (r >> 2) + 4 * (lane >> 5);
            S[row * 68 + (lane & 31)]      = acc0[r];
            S[row * 68 + 32 + (lane & 31)] = acc1[r];
        }
    }
    __syncthreads();
    if (wv < 2) {
        const float* S = (wv == 0) ? S0 : S1;
#pragma unroll
        for (int r = 0; r < 16; ++r) {
            const int row = (r & 3) + 8 * (r >> 2) + 4 * (lane >> 5);
            acc0[r] += S[row * 68 + (lane & 31)];
            acc1[r] += S[row * 68 + 32 + (lane & 31)];
        }
    }
    __syncthreads();
    if (wv == 1) {
#pragma unroll
        for (int r = 0; r < 16; ++r) {
            const int row = (r & 3) + 8 * (r >> 2) + 4 * (lane >> 5);
            S1[row * 68 + (lane & 31)]      = acc0[r];
            S1[row * 68 + 32 + (lane & 31)] = acc1[r];
        }
    }
    __syncthreads();
    if (wv == 0) {
#pragma unroll
        for (int r = 0; r < 16; ++r) {
            const int row = (r & 3) + 8 * (r >> 2) + 4 * (lane >> 5);
            const float v0 = acc0[r] + S1[row * 68 + (lane & 31)];
            const float v1 = acc1[r] + S1[row * 68 + 32 + (lane & 31)];
            S0[row * 68 + (lane & 31)]      = v0;
            S0[row * 68 + 32 + (lane & 31)] = v1;
        }
    }
    __syncthreads();

    if (wv == 0) {
        // coalesced logits store: 8 x (4 rows x 16 lanes x 16B)
#pragma unroll
        for (int p = 0; p < 8; ++p) {
            const int row = p * 4 + (lane >> 4);
            const int c4  = lane & 15;
            const float4 v = *reinterpret_cast<const float4*>(&S0[row * 68 + c4 * 4]);
            *reinterpret_cast<float4*>(&logits[(tokBase + row) * NEXP + c4 * 4]) = v;
        }
    } else if (wv == 1 && lane < 32) {
        // top-9 scan, lane = token (static indexing only)
        const int t = lane;
        float v[NEXP];
#pragma unroll
        for (int q = 0; q < 16; ++q) {
            const float4 f = *reinterpret_cast<const float4*>(&S0[t * 68 + 4 * q]);
            v[4 * q + 0] = f.x; v[4 * q + 1] = f.y;
            v[4 * q + 2] = f.z; v[4 * q + 3] = f.w;
        }
        float bv[NSCAN];
        int   bidx[NSCAN];
        unsigned long long used = 0ull;
#pragma unroll
        for (int k = 0; k < NSCAN; ++k) {
            float best = -INFINITY;
            int   bi   = 0;
#pragma unroll
            for (int i = 0; i < NEXP; ++i) {
                const bool avail = ((used >> i) & 1ull) == 0ull;
                if (avail && v[i] > best) { best = v[i]; bi = i; }
            }
            bv[k] = best; bidx[k] = bi; used |= (1ull << bi);
        }
        float ming = bv[0] - bv[1];
#pragma unroll
        for (int k = 1; k < NSCAN - 1; ++k) ming = fminf(ming, bv[k] - bv[k + 1]);
        const size_t gt = tokBase + t;
        if (ming < TAU) {
            const int pos = atomicAdd(cnt, 1);   // order-free: fixup per-token
            list[pos] = (int)gt;
        }
        const float m = bv[0];
        float ek[TOPK];
        float s = 0.f;
#pragma unroll
        for (int k = 0; k < TOPK; ++k) { ek[k] = expf(bv[k] - m); s += ek[k]; }
        const float inv = 1.0f / s;
#pragma unroll
        for (int k = 0; k < TOPK; ++k) {
            selw[gt * TOPK + k]   = ek[k] * inv;
            selidx[gt * TOPK + k] = (float)bidx[k];
        }
    }
}

// ---- fixup: fp64 re-dot + exact top-8; 1 block (4-wave k-split) / token --
__global__ __launch_bounds__(256) void gate_fixup_f64(
    const float* __restrict__ hidden,
    const float* __restrict__ wgate,
    const int* __restrict__ cnt,
    const int* __restrict__ list,
    float* __restrict__ selw,
    float* __restrict__ selidx)
{
    __shared__ double red[4][64];
    const int tid  = threadIdx.x;
    const int lane = tid & 63;
    const int wv   = tid >> 6;
    const int n    = *cnt;

    for (int i = blockIdx.x; i < n; i += gridDim.x) {
        const int t = list[i];
        const float* hrow = &hidden[(size_t)t * HDIM + wv * 512];
        const float* wrow = &wgate[(size_t)lane * HDIM + wv * 512];

        double a0 = 0.0, a1 = 0.0, a2 = 0.0, a3 = 0.0;
#pragma unroll 2
        for (int k = 0; k < 512; k += 16) {
            const float4 h0 = *reinterpret_cast<const float4*>(&hrow[k +  0]);
            const float4 h1 = *reinterpret_cast<const float4*>(&hrow[k +  4]);
            const float4 h2 = *reinterpret_cast<const float4*>(&hrow[k +  8]);
            const float4 h3 = *reinterpret_cast<const float4*>(&hrow[k + 12]);
            const float4 w0 = *reinterpret_cast<const float4*>(&wrow[k +  0]);
            const float4 w1 = *reinterpret_cast<const float4*>(&wrow[k +  4]);
            const float4 w2 = *reinterpret_cast<const float4*>(&wrow[k +  8]);
            const float4 w3 = *reinterpret_cast<const float4*>(&wrow[k + 12]);
            a0 += (double)h0.x * w0.x + (double)h0.y * w0.y
                + (double)h0.z * w0.z + (double)h0.w * w0.w;
            a1 += (double)h1.x * w1.x + (double)h1.y * w1.y
                + (double)h1.z * w1.z + (double)h1.w * w1.w;
            a2 += (double)h2.x * w2.x + (double)h2.y * w2.y
                + (double)h2.z * w2.z + (double)h2.w * w2.w;
            a3 += (double)h3.x * w3.x + (double)h3.y * w3.y
                + (double)h3.z * w3.z + (double)h3.w * w3.w;
        }
        red[wv][lane] = (a0 + a1) + (a2 + a3);
        __syncthreads();
        if (wv == 0) {
            double v  = red[0][lane] + red[1][lane] + red[2][lane] + red[3][lane];
            int    id = lane;
            double bv[TOPK];
            int    bidx[TOPK];
#pragma unroll
            for (int p = 0; p < TOPK; ++p) {
                double mv = v;
                int    mi = id;
#pragma unroll
                for (int off = 32; off >= 1; off >>= 1) {
                    const double ov = __shfl_xor(mv, off);
                    const int    oi = __shfl_xor(mi, off);
                    if (ov > mv || (ov == mv && oi < mi)) { mv = ov; mi = oi; }
                }
                bv[p] = mv; bidx[p] = mi;
                if (id == mi) v = -INFINITY;
            }
            if (lane == 0) {
                float ek[TOPK];
                float s = 0.f;
#pragma unroll
                for (int p = 0; p < TOPK; ++p) {
                    ek[p] = expf((float)(bv[p] - bv[0]));
                    s += ek[p];
                }
                const float inv = 1.0f / s;
#pragma unroll
                for (int p = 0; p < TOPK; ++p) {
                    selw[(size_t)t * TOPK + p]   = ek[p] * inv;
                    selidx[(size_t)t * TOPK + p] = (float)bidx[p];
                }
            }
        }
        __syncthreads();   // red reused next iteration
    }
}

extern "C" void kernel_launch(void* const* d_in, const int* in_sizes, int n_in,
                              void* d_out, int out_size, void* d_ws, size_t ws_size,
                              hipStream_t stream) {
    const float* hidden = (const float*)d_in[0];   // [4,4096,2048] f32
    const float* wgate  = (const float*)d_in[1];   // [64,2048] f32

    const int T = in_sizes[0] / HDIM;              // 16384 tokens

    float* out    = (float*)d_out;
    float* selw   = out;                           // T*8
    float* selidx = out + (size_t)T * TOPK;        // T*8
    float* logits = out + (size_t)2 * T * TOPK;    // T*64

    uint4* wf   = (uint4*)d_ws;                    // 512 KiB frag records
    int*   cnt  = (int*)((char*)d_ws + 524288);
    int*   list = cnt + 64;

    hipMemsetAsync(cnt, 0, 256, stream);

    prep_wfrag<<<128, 128, 0, stream>>>(wgate, wf);
    gate_fused<<<T / 32, 256, 0, stream>>>(hidden, wf, logits,
                                           selw, selidx, cnt, list);
    gate_fixup_f64<<<512, 256, 0, stream>>>(hidden, wgate, cnt, list,
                                            selw, selidx);
}